// Round 23
// baseline (1529.770 us; speedup 1.0000x reference)
//
#include <hip/hip_runtime.h>
#include <hip/hip_bf16.h>

// Combine: round-16 proven form + degree-sorted node permutation (counting
// sort) so each wave's 8 nodes have ~equal degree -> rounds ~= mean degree
// instead of max-of-8 (~45% of gather load slots were dead predication).

#define NN 100000   // nodes
#define NV 50000    // vars
#define NE 640000   // edges
#define FEAT 16
#define HD 128
#define NL 4
#define NI 20000    // n_int
#define KK 8
#define SCAN_BLK 98 // ceil(NN / 1024)
#define LDP 136     // padded LDS row stride (bf16 elems)
#define WE_STRIDE (128*32 + 128*128)   // per-side embed weight stride (ushorts)
#define NDBUCK 256  // degree buckets for counting sort

typedef __hip_bfloat16 bf16;
typedef __attribute__((ext_vector_type(8))) short short8;
typedef __attribute__((ext_vector_type(4))) float f32x4;

static __device__ __forceinline__ ushort f2bu(float f) {
    __hip_bfloat16 b = __float2bfloat16(f);
    return *reinterpret_cast<ushort*>(&b);
}
static __device__ __forceinline__ float bu2f(ushort u) {
    __hip_bfloat16 b = *reinterpret_cast<__hip_bfloat16*>(&u);
    return __bfloat162float(b);
}

// ---------------- degree / norm ----------------
__global__ void k_deg_init(float* deg) {
    int i = blockIdx.x * blockDim.x + threadIdx.x;
    if (i < NN) deg[i] = 1.0f;
}

__global__ void k_deg_scatter(const int* __restrict__ ei, float* deg) {
    int e = blockIdx.x * blockDim.x + threadIdx.x;
    if (e < NE) atomicAdd(&deg[ei[NE + e]], 1.0f);
}

__global__ void k_deg_fin(const float* __restrict__ deg, float* dinv, float* selfn) {
    int i = blockIdx.x * blockDim.x + threadIdx.x;
    if (i < NN) {
        float d = deg[i];
        dinv[i]  = rsqrtf(d);
        selfn[i] = 1.0f / d;
    }
}

// ---------------- multi-block exclusive scan of in-degree counts ----------------
__global__ void k_scan_part(const float* __restrict__ deg, int* __restrict__ part) {
    __shared__ int s[256];
    const int t = threadIdx.x;
    const int i = blockIdx.x * 1024 + t * 4;
    int sum = 0;
#pragma unroll
    for (int j = 0; j < 4; ++j)
        if (i + j < NN) sum += (int)deg[i + j] - 1;
    s[t] = sum;
    __syncthreads();
    for (int off = 128; off > 0; off >>= 1) {
        if (t < off) s[t] += s[t + off];
        __syncthreads();
    }
    if (t == 0) part[blockIdx.x] = s[0];
}

__global__ void k_scan_mid(const int* __restrict__ part, int* __restrict__ blockoff,
                           int* __restrict__ row_ptr) {
    __shared__ int s[128];
    const int t = threadIdx.x;
    int v = (t < SCAN_BLK) ? part[t] : 0;
    s[t] = v;
    __syncthreads();
    for (int off = 1; off < 128; off <<= 1) {
        int u = (t >= off) ? s[t - off] : 0;
        __syncthreads();
        s[t] += u;
        __syncthreads();
    }
    if (t < SCAN_BLK) blockoff[t] = s[t] - v;   // exclusive
    if (t == 0) row_ptr[NN] = NE;
}

__global__ void k_scan_apply(const float* __restrict__ deg,
                             const int* __restrict__ blockoff,
                             int* __restrict__ row_ptr, int* __restrict__ cnt) {
    __shared__ int s[256];
    const int t = threadIdx.x;
    const int i = blockIdx.x * 1024 + t * 4;
    int c[4];
    int tsum = 0;
#pragma unroll
    for (int j = 0; j < 4; ++j) {
        c[j] = (i + j < NN) ? (int)deg[i + j] - 1 : 0;
        tsum += c[j];
    }
    s[t] = tsum;
    __syncthreads();
    for (int off = 1; off < 256; off <<= 1) {
        int u = (t >= off) ? s[t - off] : 0;
        __syncthreads();
        s[t] += u;
        __syncthreads();
    }
    int off = blockoff[blockIdx.x] + s[t] - tsum;   // exclusive within block
#pragma unroll
    for (int j = 0; j < 4; ++j) {
        if (i + j < NN) {
            row_ptr[i + j] = off;
            cnt[i + j] = 0;
            off += c[j];
        }
    }
}

__global__ void k_csr_fill(const int* __restrict__ ei,
                           const int* __restrict__ row_ptr, int* __restrict__ cnt,
                           const float* __restrict__ dinv,
                           int* __restrict__ col, float* __restrict__ wgt) {
    int e = blockIdx.x * blockDim.x + threadIdx.x;
    if (e >= NE) return;
    const int s = ei[e];
    const int d = ei[NE + e];
    const int pos = row_ptr[d] + atomicAdd(&cnt[d], 1);
    col[pos] = s;
    wgt[pos] = dinv[s] * dinv[d];
}

// ---------------- counting sort of nodes by in-degree ----------------
__global__ void k_hist_init(int* dhist, int* dcnt2) {
    int i = threadIdx.x;
    dhist[i] = 0;
    dcnt2[i] = 0;
}

__global__ void k_hist(const float* __restrict__ deg, int* __restrict__ dhist) {
    int i = blockIdx.x * blockDim.x + threadIdx.x;
    if (i < NN) {
        int d = (int)deg[i] - 1;
        atomicAdd(&dhist[d < NDBUCK ? d : NDBUCK - 1], 1);
    }
}

__global__ void k_hist_scan(const int* __restrict__ dhist, int* __restrict__ dbase) {
    __shared__ int s[NDBUCK];
    const int t = threadIdx.x;
    int v = dhist[t];
    s[t] = v;
    __syncthreads();
    for (int off = 1; off < NDBUCK; off <<= 1) {
        int u = (t >= off) ? s[t - off] : 0;
        __syncthreads();
        s[t] += u;
        __syncthreads();
    }
    dbase[t] = s[t] - v;   // exclusive
}

__global__ void k_perm_fill(const float* __restrict__ deg,
                            const int* __restrict__ dbase, int* __restrict__ dcnt2,
                            int* __restrict__ perm) {
    int i = blockIdx.x * blockDim.x + threadIdx.x;
    if (i < NN) {
        int d = (int)deg[i] - 1;
        d = d < NDBUCK ? d : NDBUCK - 1;
        const int pos = dbase[d] + atomicAdd(&dcnt2[d], 1);
        perm[pos] = i;
    }
}

// ---------------- weight prep: conv/refine fp32 [k][j] -> bf16 transposed [j][k] ----------------
__global__ void k_wprep(const float* __restrict__ conv_W,
                        const float* __restrict__ ref_W1,
                        const float* __restrict__ ref_W2,
                        ushort* __restrict__ wt) {
    const int mat = blockIdx.x >> 7;
    const int j = blockIdx.x & 127;
    const int k = threadIdx.x;
    const float* src = (mat < 4) ? conv_W + (size_t)mat * HD * HD
                     : (mat < 8) ? ref_W1 + (size_t)(mat - 4) * HD * HD
                                 : ref_W2 + (size_t)(mat - 8) * HD * HD;
    wt[(size_t)mat * HD * HD + j * HD + k] = f2bu(src[k * HD + j]);
}

// ---------------- embed weight prep ----------------
__global__ void k_wprep_embed(const float* __restrict__ vW1, const float* __restrict__ vW2,
                              const float* __restrict__ cW1, const float* __restrict__ cW2,
                              ushort* __restrict__ wte) {
    const int side = blockIdx.x >> 7;
    const int j = blockIdx.x & 127;
    const int k = threadIdx.x;   // 0..127
    const float* W1 = side ? cW1 : vW1;
    const float* W2 = side ? cW2 : vW2;
    ushort* o = wte + (size_t)side * WE_STRIDE;
    if (k < 32) o[j * 32 + k] = (k < FEAT) ? f2bu(W1[k * HD + j]) : (ushort)0;
    o[128 * 32 + j * HD + k] = f2bu(W2[k * HD + j]);
}

// ---------------- embedding MLP via MFMA; writes hb + hw(layer0) ----------------
__global__ __launch_bounds__(256, 4) void k_embed_mfma(
        const float* __restrict__ x,
        const ushort* __restrict__ W1t, const float* __restrict__ b1,
        const ushort* __restrict__ W2t, const float* __restrict__ b2,
        const ushort* __restrict__ Wtc,
        int nbase, int nend,
        ushort* __restrict__ hb, ushort* __restrict__ hwb) {
    const int lane = threadIdx.x & 63, w = threadIdx.x >> 6;
    const int l15 = lane & 15, lg = lane >> 4;
    const int rowb = nbase + blockIdx.x * 128;
    __shared__ ushort hsm[128][LDP];

#pragma unroll
    for (int rt = 0; rt < 2; ++rt) {
        const int r = rowb + w * 32 + rt * 16 + l15;
        const int rc = r < nend ? r : nend - 1;
        short8 a = {0, 0, 0, 0, 0, 0, 0, 0};
        if (lg < 2) {
            const float* xp = x + (size_t)rc * FEAT + lg * 8;
#pragma unroll
            for (int i = 0; i < 8; ++i) a[i] = (short)f2bu(xp[i]);
        }
#pragma unroll
        for (int jt = 0; jt < 8; ++jt) {
            const float bv = b1[jt * 16 + l15];
            f32x4 acc = {bv, bv, bv, bv};
            short8 b = *reinterpret_cast<const short8*>(&W1t[(jt * 16 + l15) * 32 + lg * 8]);
            acc = __builtin_amdgcn_mfma_f32_16x16x32_bf16(a, b, acc, 0, 0, 0);
#pragma unroll
            for (int rr = 0; rr < 4; ++rr)
                hsm[w * 32 + rt * 16 + lg * 4 + rr][jt * 16 + l15] =
                    f2bu(fmaxf(acc[rr], 0.0f));
        }
    }
    __syncthreads();

#pragma unroll
    for (int rt = 0; rt < 2; ++rt) {
        f32x4 acc[8];
#pragma unroll
        for (int jt = 0; jt < 8; ++jt) {
            const float bv = b2[jt * 16 + l15];
            f32x4 v = {bv, bv, bv, bv};
            acc[jt] = v;
        }
#pragma unroll
        for (int ks = 0; ks < 4; ++ks) {
            short8 a = *reinterpret_cast<const short8*>(&hsm[w * 32 + rt * 16 + l15][ks * 32 + lg * 8]);
#pragma unroll
            for (int jt = 0; jt < 8; ++jt) {
                short8 b = *reinterpret_cast<const short8*>(&W2t[(jt * 16 + l15) * HD + ks * 32 + lg * 8]);
                acc[jt] = __builtin_amdgcn_mfma_f32_16x16x32_bf16(a, b, acc[jt], 0, 0, 0);
            }
        }
#pragma unroll
        for (int jt = 0; jt < 8; ++jt)
#pragma unroll
            for (int rr = 0; rr < 4; ++rr) {
                const int row = rowb + w * 32 + rt * 16 + lg * 4 + rr;
                const ushort hv = f2bu(acc[jt][rr]);
                if (row < nend) hb[(size_t)row * HD + jt * 16 + l15] = hv;
                hsm[w * 32 + rt * 16 + lg * 4 + rr][jt * 16 + l15] = hv;
            }
        f32x4 acc3[8];
        const f32x4 zero = {0.f, 0.f, 0.f, 0.f};
#pragma unroll
        for (int jt = 0; jt < 8; ++jt) acc3[jt] = zero;
#pragma unroll
        for (int ks = 0; ks < 4; ++ks) {
            short8 a = *reinterpret_cast<const short8*>(&hsm[w * 32 + rt * 16 + l15][ks * 32 + lg * 8]);
#pragma unroll
            for (int jt = 0; jt < 8; ++jt) {
                short8 b = *reinterpret_cast<const short8*>(&Wtc[(jt * 16 + l15) * HD + ks * 32 + lg * 8]);
                acc3[jt] = __builtin_amdgcn_mfma_f32_16x16x32_bf16(a, b, acc3[jt], 0, 0, 0);
            }
        }
#pragma unroll
        for (int jt = 0; jt < 8; ++jt)
#pragma unroll
            for (int rr = 0; rr < 4; ++rr) {
                const int row = rowb + w * 32 + rt * 16 + lg * 4 + rr;
                if (row < nend)
                    hwb[(size_t)row * HD + jt * 16 + l15] = f2bu(acc3[jt][rr]);
            }
    }
}

// ---------------- hw = h @ conv_W[l]  (bf16 MFMA, bf16 out) ----------------
__global__ __launch_bounds__(256) void k_hw(
                     const ushort* __restrict__ hb, const ushort* __restrict__ Wt,
                     ushort* __restrict__ hwb) {
    const int lane = threadIdx.x & 63;
    const int w = threadIdx.x >> 6;
    const int row0 = blockIdx.x * 128 + w * 32;
    const int l15 = lane & 15, lg = lane >> 4;

    const f32x4 zero = {0.f, 0.f, 0.f, 0.f};
    f32x4 acc[2][8];
#pragma unroll
    for (int rt = 0; rt < 2; ++rt)
#pragma unroll
        for (int jt = 0; jt < 8; ++jt) acc[rt][jt] = zero;

#pragma unroll
    for (int ks = 0; ks < 4; ++ks) {
        short8 a[2];
#pragma unroll
        for (int rt = 0; rt < 2; ++rt) {
            int r = row0 + rt * 16 + l15;
            r = r < NN ? r : NN - 1;
            a[rt] = *reinterpret_cast<const short8*>(&hb[(size_t)r * HD + ks * 32 + lg * 8]);
        }
#pragma unroll
        for (int jt = 0; jt < 8; ++jt) {
            short8 b = *reinterpret_cast<const short8*>(&Wt[(jt * 16 + l15) * HD + ks * 32 + lg * 8]);
            acc[0][jt] = __builtin_amdgcn_mfma_f32_16x16x32_bf16(a[0], b, acc[0][jt], 0, 0, 0);
            acc[1][jt] = __builtin_amdgcn_mfma_f32_16x16x32_bf16(a[1], b, acc[1][jt], 0, 0, 0);
        }
    }
#pragma unroll
    for (int rt = 0; rt < 2; ++rt)
#pragma unroll
        for (int jt = 0; jt < 8; ++jt)
#pragma unroll
            for (int r = 0; r < 4; ++r) {
                int row = row0 + rt * 16 + lg * 4 + r;
                if (row < NN) hwb[(size_t)row * HD + jt * 16 + l15] = f2bu(acc[rt][jt][r]);
            }
}

// ---------------- gather + combine + refine MLP (MFMA) + bf16 residual ----------------
// Round-16 form + degree-sorted perm: block handles nodes perm[n0..n0+63],
// all ~equal degree -> rounds ~= degree (not max-of-8). pm=-1 marks tail.
__global__ __launch_bounds__(512, 4) void k_combine(
                          const ushort* __restrict__ hwb,
                          const int* __restrict__ row_ptr,
                          const int* __restrict__ col,
                          const float* __restrict__ wgt,
                          const float* __restrict__ selfn,
                          const float* __restrict__ cb,
                          const ushort* __restrict__ Wt1, const float* __restrict__ b1,
                          const ushort* __restrict__ Wt2, const float* __restrict__ b2,
                          ushort* __restrict__ hb,
                          const int* __restrict__ perm) {
    const int t = threadIdx.x;
    const int n0 = blockIdx.x * 64;
    __shared__ ushort hs[64][LDP];
    __shared__ ushort hid[64][LDP];
    __shared__ int pm[64];
    __shared__ int rp0[64], rp1[64];

    if (t < 64) {
        const int idx = n0 + t;
        const int node = (idx < NN) ? perm[idx] : -1;
        pm[t] = node;
        const int nc = node >= 0 ? node : 0;
        rp0[t] = row_ptr[nc];
        rp1[t] = node >= 0 ? row_ptr[nc + 1] : row_ptr[nc];
    }
    __syncthreads();

    const int lane = t & 63, w = t >> 6;
    {   // gather phase (2-cluster form)
        const int c0 = 2 * lane;
        const float cbx = cb[c0], cby = cb[c0 + 1];
        float accx[8], accy[8];
        int ecur[8], eend[8];
        int rounds = 0;
#pragma unroll
        for (int m = 0; m < 8; ++m) {
            const int node = pm[w * 8 + m];
            const int nc = node >= 0 ? node : 0;
            const uint hv = *reinterpret_cast<const uint*>(&hwb[(size_t)nc * HD + c0]);
            const float sn = selfn[nc];
            accx[m] = bu2f((ushort)(hv & 0xffffu)) * sn + cbx;
            accy[m] = bu2f((ushort)(hv >> 16)) * sn + cby;
            ecur[m] = rp0[w * 8 + m];
            eend[m] = rp1[w * 8 + m];
            rounds = max(rounds, eend[m] - ecur[m]);
        }
#pragma unroll 1
        for (int r = 0; r < rounds; r += 2) {
            uint va[8], vb[8];
            float wa[8], wb[8];
            int ca[8], cc[8];
#pragma unroll
            for (int m = 0; m < 8; ++m) {
                const int e0 = ecur[m];
                const int a0 = (e0 < eend[m]) ? e0 : 0;
                const int a1 = (e0 + 1 < eend[m]) ? e0 + 1 : 0;
                wa[m] = (e0 < eend[m]) ? wgt[a0] : 0.0f;
                wb[m] = (e0 + 1 < eend[m]) ? wgt[a1] : 0.0f;
                ca[m] = col[a0];
                cc[m] = col[a1];
            }
#pragma unroll
            for (int m = 0; m < 8; ++m) {
                va[m] = *reinterpret_cast<const uint*>(&hwb[(size_t)ca[m] * HD + c0]);
                vb[m] = *reinterpret_cast<const uint*>(&hwb[(size_t)cc[m] * HD + c0]);
            }
#pragma unroll
            for (int m = 0; m < 8; ++m) {
                accx[m] += wa[m] * bu2f((ushort)(va[m] & 0xffffu));
                accy[m] += wa[m] * bu2f((ushort)(va[m] >> 16));
                accx[m] += wb[m] * bu2f((ushort)(vb[m] & 0xffffu));
                accy[m] += wb[m] * bu2f((ushort)(vb[m] >> 16));
            }
#pragma unroll
            for (int m = 0; m < 8; ++m) ecur[m] += 2;
        }
#pragma unroll
        for (int m = 0; m < 8; ++m) {
            const uint px = (uint)f2bu(fmaxf(accx[m], 0.0f));
            const uint py = (uint)f2bu(fmaxf(accy[m], 0.0f));
            *reinterpret_cast<uint*>(&hs[w * 8 + m][c0]) = px | (py << 16);
        }
    }
    __syncthreads();

    const int l15 = lane & 15, lg = lane >> 4;
    const int rt = (w & 3) * 16;           // row-tile base within block
    const int c0 = (w >> 2) * 64;          // col half base

    // GEMM1: hid = relu(hs @ W1 + b1)
    f32x4 acc1[4];
#pragma unroll
    for (int jt = 0; jt < 4; ++jt) {
        float bv = b1[c0 + jt * 16 + l15];
        f32x4 v = {bv, bv, bv, bv};
        acc1[jt] = v;
    }
#pragma unroll
    for (int ks = 0; ks < 4; ++ks) {
        short8 a = *reinterpret_cast<const short8*>(&hs[rt + l15][ks * 32 + lg * 8]);
#pragma unroll
        for (int jt = 0; jt < 4; ++jt) {
            short8 b = *reinterpret_cast<const short8*>(&Wt1[(c0 + jt * 16 + l15) * HD + ks * 32 + lg * 8]);
            acc1[jt] = __builtin_amdgcn_mfma_f32_16x16x32_bf16(a, b, acc1[jt], 0, 0, 0);
        }
    }
#pragma unroll
    for (int jt = 0; jt < 4; ++jt)
#pragma unroll
        for (int r = 0; r < 4; ++r)
            hid[rt + lg * 4 + r][c0 + jt * 16 + l15] = f2bu(fmaxf(acc1[jt][r], 0.0f));
    __syncthreads();

    // GEMM2: out = hid @ W2 + b2; hb[perm] += out (bf16 residual)
    f32x4 acc2[4];
#pragma unroll
    for (int jt = 0; jt < 4; ++jt) {
        float bv = b2[c0 + jt * 16 + l15];
        f32x4 v = {bv, bv, bv, bv};
        acc2[jt] = v;
    }
#pragma unroll
    for (int ks = 0; ks < 4; ++ks) {
        short8 a = *reinterpret_cast<const short8*>(&hid[rt + l15][ks * 32 + lg * 8]);
#pragma unroll
        for (int jt = 0; jt < 4; ++jt) {
            short8 b = *reinterpret_cast<const short8*>(&Wt2[(c0 + jt * 16 + l15) * HD + ks * 32 + lg * 8]);
            acc2[jt] = __builtin_amdgcn_mfma_f32_16x16x32_bf16(a, b, acc2[jt], 0, 0, 0);
        }
    }
#pragma unroll
    for (int jt = 0; jt < 4; ++jt)
#pragma unroll
        for (int r = 0; r < 4; ++r) {
            const int node = pm[rt + lg * 4 + r];
            if (node >= 0) {
                const size_t idx = (size_t)node * HD + c0 + jt * 16 + l15;
                hb[idx] = f2bu(acc2[jt][r] + bu2f(hb[idx]));
            }
        }
}

// ---------------- bernoulli head: (128 -> 64 -> 1), bf16 input ----------------
__global__ void k_bern(const ushort* __restrict__ hb,
                       const float* __restrict__ W1, const float* __restrict__ b1,
                       const float* __restrict__ W2, const float* __restrict__ b2,
                       float* __restrict__ out) {
    const long long t = (long long)blockIdx.x * blockDim.x + threadIdx.x;
    const int n = (int)(t >> 6);
    const int lane = (int)(t & 63);
    if (n >= NV) return;
    const ushort* hn = hb + (size_t)n * HD;
    float acc = b1[lane];
#pragma unroll 8
    for (int k = 0; k < HD; ++k) acc += bu2f(hn[k]) * W1[k * 64 + lane];
    float p = fmaxf(acc, 0.0f) * W2[lane];
#pragma unroll
    for (int off = 32; off > 0; off >>= 1) p += __shfl_down(p, off);
    if (lane == 0) out[n] = p + b2[0];
}

// ---------------- categorical head ----------------
__global__ void k_cat(const ushort* __restrict__ hb,
                      const float* __restrict__ cW, const float* __restrict__ cb,
                      float* __restrict__ out) {
    const long long t = (long long)blockIdx.x * blockDim.x + threadIdx.x;
    const int n = (int)(t >> 6);
    const int lane = (int)(t & 63);
    if (n >= NI) return;
    const ushort* hn = hb + (size_t)n * HD;
    float p[KK];
#pragma unroll
    for (int k = 0; k < KK; ++k) p[k] = 0.0f;
#pragma unroll
    for (int half = 0; half < 2; ++half) {
        const int hh = lane + 64 * half;
        const float vh = bu2f(hn[hh]);
        const float* wp = cW + ((size_t)n * HD + hh) * KK;
        const float4 w0 = *reinterpret_cast<const float4*>(wp);
        const float4 w1 = *reinterpret_cast<const float4*>(wp + 4);
        p[0] += vh * w0.x; p[1] += vh * w0.y; p[2] += vh * w0.z; p[3] += vh * w0.w;
        p[4] += vh * w1.x; p[5] += vh * w1.y; p[6] += vh * w1.z; p[7] += vh * w1.w;
    }
#pragma unroll
    for (int k = 0; k < KK; ++k) {
#pragma unroll
        for (int off = 32; off > 0; off >>= 1) p[k] += __shfl_down(p[k], off);
    }
    if (lane == 0) {
#pragma unroll
        for (int k = 0; k < KK; ++k) out[NV + (size_t)n * KK + k] = p[k] + cb[(size_t)n * KK + k];
    }
}

extern "C" void kernel_launch(void* const* d_in, const int* in_sizes, int n_in,
                              void* d_out, int out_size, void* d_ws, size_t ws_size,
                              hipStream_t stream) {
    const float* x  = (const float*)d_in[0];
    const int*   ei = (const int*)d_in[1];   // int inputs arrive as int32
    // d_in[2] = num_vars scalar (hardcoded NV)
    const float* ve_W1 = (const float*)d_in[3];
    const float* ve_b1 = (const float*)d_in[4];
    const float* ve_W2 = (const float*)d_in[5];
    const float* ve_b2 = (const float*)d_in[6];
    const float* ce_W1 = (const float*)d_in[7];
    const float* ce_b1 = (const float*)d_in[8];
    const float* ce_W2 = (const float*)d_in[9];
    const float* ce_b2 = (const float*)d_in[10];
    const float* conv_W = (const float*)d_in[11];
    const float* conv_b = (const float*)d_in[12];
    const float* ref_W1 = (const float*)d_in[13];
    const float* ref_b1 = (const float*)d_in[14];
    const float* ref_W2 = (const float*)d_in[15];
    const float* ref_b2 = (const float*)d_in[16];
    const float* bh_W1 = (const float*)d_in[17];
    const float* bh_b1 = (const float*)d_in[18];
    const float* bh_W2 = (const float*)d_in[19];
    const float* bh_b2 = (const float*)d_in[20];
    const float* cat_W = (const float*)d_in[21];
    const float* cat_b = (const float*)d_in[22];
    float* out = (float*)d_out;

    // ---- workspace layout (~86 MiB total) ----
    const size_t need = (size_t)(3 * NN + (NN + 1) + NN + 2 * NE + 2 * SCAN_BLK) * 4
                      + (size_t)3 * NN * HD * 2        // hwbA, hwbB(spare), hb bf16
                      + (size_t)12 * HD * HD * 2       // wt bf16
                      + (size_t)2 * WE_STRIDE * 2      // wte bf16
                      + (size_t)(3 * NDBUCK + NN) * 4; // hist + perm
    if (ws_size < need) return;

    float* deg     = (float*)d_ws;                   // NN
    float* dinv    = deg + NN;                       // NN
    float* selfn   = dinv + NN;                      // NN
    int*   row_ptr = (int*)(selfn + NN);             // NN+1
    int*   cnt     = row_ptr + (NN + 1);             // NN
    int*   col     = cnt + NN;                       // NE
    float* wgt     = (float*)(col + NE);             // NE
    int*   part    = (int*)(wgt + NE);               // SCAN_BLK
    int*   blockoff= part + SCAN_BLK;                // SCAN_BLK
    ushort* hwbA   = (ushort*)(blockoff + SCAN_BLK); // NN*HD bf16
    ushort* hwbB   = hwbA + (size_t)NN * HD;         // NN*HD bf16 (unused spare)
    ushort* hb     = hwbB + (size_t)NN * HD;         // NN*HD bf16
    ushort* wt     = hb + (size_t)NN * HD;           // 12*HD*HD bf16
    ushort* wte    = wt + (size_t)12 * HD * HD;      // 2*WE_STRIDE bf16
    int*   dhist   = (int*)(wte + (size_t)2 * WE_STRIDE); // NDBUCK
    int*   dbase   = dhist + NDBUCK;                 // NDBUCK
    int*   dcnt2   = dbase + NDBUCK;                 // NDBUCK
    int*   perm    = dcnt2 + NDBUCK;                 // NN

    // degree / norms / CSR / sort / weight prep
    k_deg_init<<<(NN + 255) / 256, 256, 0, stream>>>(deg);
    k_deg_scatter<<<(NE + 255) / 256, 256, 0, stream>>>(ei, deg);
    k_deg_fin<<<(NN + 255) / 256, 256, 0, stream>>>(deg, dinv, selfn);
    k_scan_part<<<SCAN_BLK, 256, 0, stream>>>(deg, part);
    k_scan_mid<<<1, 128, 0, stream>>>(part, blockoff, row_ptr);
    k_scan_apply<<<SCAN_BLK, 256, 0, stream>>>(deg, blockoff, row_ptr, cnt);
    k_csr_fill<<<(NE + 255) / 256, 256, 0, stream>>>(ei, row_ptr, cnt, dinv, col, wgt);
    k_hist_init<<<1, NDBUCK, 0, stream>>>(dhist, dcnt2);
    k_hist<<<(NN + 255) / 256, 256, 0, stream>>>(deg, dhist);
    k_hist_scan<<<1, NDBUCK, 0, stream>>>(dhist, dbase);
    k_perm_fill<<<(NN + 255) / 256, 256, 0, stream>>>(deg, dbase, dcnt2, perm);
    k_wprep<<<12 * 128, 128, 0, stream>>>(conv_W, ref_W1, ref_W2, wt);
    k_wprep_embed<<<256, 128, 0, stream>>>(ve_W1, ve_W2, ce_W1, ce_W2, wte);

    // embedding (MFMA) + fused conv_W[0] matmul, per side
    k_embed_mfma<<<(NV + 127) / 128, 256, 0, stream>>>(
        x, wte, ve_b1, wte + 128 * 32, ve_b2, wt, 0, NV, hb, hwbA);
    k_embed_mfma<<<(NN - NV + 127) / 128, 256, 0, stream>>>(
        x, wte + WE_STRIDE, ce_b1, wte + WE_STRIDE + 128 * 32, ce_b2, wt, NV, NN, hb, hwbA);

    // conv layers
    for (int l = 0; l < NL; ++l) {
        if (l > 0)
            k_hw<<<(NN + 127) / 128, 256, 0, stream>>>(hb, wt + (size_t)l * HD * HD, hwbA);
        k_combine<<<(NN + 63) / 64, 512, 0, stream>>>(hwbA, row_ptr, col, wgt, selfn,
                                               conv_b + (size_t)l * HD,
                                               wt + (size_t)(4 + l) * HD * HD,
                                               ref_b1 + (size_t)l * HD,
                                               wt + (size_t)(8 + l) * HD * HD,
                                               ref_b2 + (size_t)l * HD,
                                               hb, perm);
    }

    // heads
    k_bern<<<(NV * 64) / 256, 256, 0, stream>>>(hb, bh_W1, bh_b1, bh_W2, bh_b2, out);
    k_cat<<<(NI * 64) / 256, 256, 0, stream>>>(hb, cat_W, cat_b, out);
}

// Round 24
// 803.917 us; speedup vs baseline: 1.9029x; 1.9029x over previous
//
#include <hip/hip_runtime.h>
#include <hip/hip_bf16.h>

// Degree-sort kept, but histogram/perm kernels rebuilt with per-block LDS
// aggregation: round-23's per-thread global atomics serialized ~15K-deep on
// the modal degree bucket (k_perm_fill 364us, k_hist similar).

#define NN 100000   // nodes
#define NV 50000    // vars
#define NE 640000   // edges
#define FEAT 16
#define HD 128
#define NL 4
#define NI 20000    // n_int
#define KK 8
#define SCAN_BLK 98 // ceil(NN / 1024)
#define LDP 136     // padded LDS row stride (bf16 elems)
#define WE_STRIDE (128*32 + 128*128)   // per-side embed weight stride (ushorts)
#define NDBUCK 256  // degree buckets for counting sort

typedef __hip_bfloat16 bf16;
typedef __attribute__((ext_vector_type(8))) short short8;
typedef __attribute__((ext_vector_type(4))) float f32x4;

static __device__ __forceinline__ ushort f2bu(float f) {
    __hip_bfloat16 b = __float2bfloat16(f);
    return *reinterpret_cast<ushort*>(&b);
}
static __device__ __forceinline__ float bu2f(ushort u) {
    __hip_bfloat16 b = *reinterpret_cast<__hip_bfloat16*>(&u);
    return __bfloat162float(b);
}

// ---------------- degree / norm ----------------
__global__ void k_deg_init(float* deg) {
    int i = blockIdx.x * blockDim.x + threadIdx.x;
    if (i < NN) deg[i] = 1.0f;
}

__global__ void k_deg_scatter(const int* __restrict__ ei, float* deg) {
    int e = blockIdx.x * blockDim.x + threadIdx.x;
    if (e < NE) atomicAdd(&deg[ei[NE + e]], 1.0f);
}

__global__ void k_deg_fin(const float* __restrict__ deg, float* dinv, float* selfn) {
    int i = blockIdx.x * blockDim.x + threadIdx.x;
    if (i < NN) {
        float d = deg[i];
        dinv[i]  = rsqrtf(d);
        selfn[i] = 1.0f / d;
    }
}

// ---------------- multi-block exclusive scan of in-degree counts ----------------
__global__ void k_scan_part(const float* __restrict__ deg, int* __restrict__ part) {
    __shared__ int s[256];
    const int t = threadIdx.x;
    const int i = blockIdx.x * 1024 + t * 4;
    int sum = 0;
#pragma unroll
    for (int j = 0; j < 4; ++j)
        if (i + j < NN) sum += (int)deg[i + j] - 1;
    s[t] = sum;
    __syncthreads();
    for (int off = 128; off > 0; off >>= 1) {
        if (t < off) s[t] += s[t + off];
        __syncthreads();
    }
    if (t == 0) part[blockIdx.x] = s[0];
}

__global__ void k_scan_mid(const int* __restrict__ part, int* __restrict__ blockoff,
                           int* __restrict__ row_ptr) {
    __shared__ int s[128];
    const int t = threadIdx.x;
    int v = (t < SCAN_BLK) ? part[t] : 0;
    s[t] = v;
    __syncthreads();
    for (int off = 1; off < 128; off <<= 1) {
        int u = (t >= off) ? s[t - off] : 0;
        __syncthreads();
        s[t] += u;
        __syncthreads();
    }
    if (t < SCAN_BLK) blockoff[t] = s[t] - v;   // exclusive
    if (t == 0) row_ptr[NN] = NE;
}

__global__ void k_scan_apply(const float* __restrict__ deg,
                             const int* __restrict__ blockoff,
                             int* __restrict__ row_ptr, int* __restrict__ cnt) {
    __shared__ int s[256];
    const int t = threadIdx.x;
    const int i = blockIdx.x * 1024 + t * 4;
    int c[4];
    int tsum = 0;
#pragma unroll
    for (int j = 0; j < 4; ++j) {
        c[j] = (i + j < NN) ? (int)deg[i + j] - 1 : 0;
        tsum += c[j];
    }
    s[t] = tsum;
    __syncthreads();
    for (int off = 1; off < 256; off <<= 1) {
        int u = (t >= off) ? s[t - off] : 0;
        __syncthreads();
        s[t] += u;
        __syncthreads();
    }
    int off = blockoff[blockIdx.x] + s[t] - tsum;   // exclusive within block
#pragma unroll
    for (int j = 0; j < 4; ++j) {
        if (i + j < NN) {
            row_ptr[i + j] = off;
            cnt[i + j] = 0;
            off += c[j];
        }
    }
}

__global__ void k_csr_fill(const int* __restrict__ ei,
                           const int* __restrict__ row_ptr, int* __restrict__ cnt,
                           const float* __restrict__ dinv,
                           int* __restrict__ col, float* __restrict__ wgt) {
    int e = blockIdx.x * blockDim.x + threadIdx.x;
    if (e >= NE) return;
    const int s = ei[e];
    const int d = ei[NE + e];
    const int pos = row_ptr[d] + atomicAdd(&cnt[d], 1);
    col[pos] = s;
    wgt[pos] = dinv[s] * dinv[d];
}

// ---------------- counting sort of nodes by in-degree (LDS-aggregated) ----------------
__global__ void k_hist_init(int* dhist, int* dcnt2) {
    int i = threadIdx.x;
    dhist[i] = 0;
    dcnt2[i] = 0;
}

__global__ void k_hist(const float* __restrict__ deg, int* __restrict__ dhist) {
    __shared__ int lh[NDBUCK];
    for (int b = threadIdx.x; b < NDBUCK; b += 256) lh[b] = 0;
    __syncthreads();
    const int i = blockIdx.x * 256 + threadIdx.x;
    if (i < NN) {
        int d = (int)deg[i] - 1;
        atomicAdd(&lh[d < NDBUCK ? d : NDBUCK - 1], 1);
    }
    __syncthreads();
    for (int b = threadIdx.x; b < NDBUCK; b += 256)
        if (lh[b]) atomicAdd(&dhist[b], lh[b]);
}

__global__ void k_hist_scan(const int* __restrict__ dhist, int* __restrict__ dbase) {
    __shared__ int s[NDBUCK];
    const int t = threadIdx.x;
    int v = dhist[t];
    s[t] = v;
    __syncthreads();
    for (int off = 1; off < NDBUCK; off <<= 1) {
        int u = (t >= off) ? s[t - off] : 0;
        __syncthreads();
        s[t] += u;
        __syncthreads();
    }
    dbase[t] = s[t] - v;   // exclusive
}

__global__ void k_perm_fill(const float* __restrict__ deg,
                            const int* __restrict__ dbase, int* __restrict__ dcnt2,
                            int* __restrict__ perm) {
    __shared__ int lcnt[NDBUCK];
    __shared__ int lbase[NDBUCK];
    for (int b = threadIdx.x; b < NDBUCK; b += 256) lcnt[b] = 0;
    __syncthreads();
    const int i = blockIdx.x * 256 + threadIdx.x;
    int d = 0, lr = 0;
    bool live = i < NN;
    if (live) {
        d = (int)deg[i] - 1;
        d = d < NDBUCK ? d : NDBUCK - 1;
        lr = atomicAdd(&lcnt[d], 1);
    }
    __syncthreads();
    for (int b = threadIdx.x; b < NDBUCK; b += 256)
        lbase[b] = lcnt[b] ? atomicAdd(&dcnt2[b], lcnt[b]) : 0;
    __syncthreads();
    if (live) perm[dbase[d] + lbase[d] + lr] = i;
}

// ---------------- weight prep: conv/refine fp32 [k][j] -> bf16 transposed [j][k] ----------------
__global__ void k_wprep(const float* __restrict__ conv_W,
                        const float* __restrict__ ref_W1,
                        const float* __restrict__ ref_W2,
                        ushort* __restrict__ wt) {
    const int mat = blockIdx.x >> 7;
    const int j = blockIdx.x & 127;
    const int k = threadIdx.x;
    const float* src = (mat < 4) ? conv_W + (size_t)mat * HD * HD
                     : (mat < 8) ? ref_W1 + (size_t)(mat - 4) * HD * HD
                                 : ref_W2 + (size_t)(mat - 8) * HD * HD;
    wt[(size_t)mat * HD * HD + j * HD + k] = f2bu(src[k * HD + j]);
}

// ---------------- embed weight prep ----------------
__global__ void k_wprep_embed(const float* __restrict__ vW1, const float* __restrict__ vW2,
                              const float* __restrict__ cW1, const float* __restrict__ cW2,
                              ushort* __restrict__ wte) {
    const int side = blockIdx.x >> 7;
    const int j = blockIdx.x & 127;
    const int k = threadIdx.x;   // 0..127
    const float* W1 = side ? cW1 : vW1;
    const float* W2 = side ? cW2 : vW2;
    ushort* o = wte + (size_t)side * WE_STRIDE;
    if (k < 32) o[j * 32 + k] = (k < FEAT) ? f2bu(W1[k * HD + j]) : (ushort)0;
    o[128 * 32 + j * HD + k] = f2bu(W2[k * HD + j]);
}

// ---------------- embedding MLP via MFMA; writes hb + hw(layer0) ----------------
__global__ __launch_bounds__(256, 4) void k_embed_mfma(
        const float* __restrict__ x,
        const ushort* __restrict__ W1t, const float* __restrict__ b1,
        const ushort* __restrict__ W2t, const float* __restrict__ b2,
        const ushort* __restrict__ Wtc,
        int nbase, int nend,
        ushort* __restrict__ hb, ushort* __restrict__ hwb) {
    const int lane = threadIdx.x & 63, w = threadIdx.x >> 6;
    const int l15 = lane & 15, lg = lane >> 4;
    const int rowb = nbase + blockIdx.x * 128;
    __shared__ ushort hsm[128][LDP];

#pragma unroll
    for (int rt = 0; rt < 2; ++rt) {
        const int r = rowb + w * 32 + rt * 16 + l15;
        const int rc = r < nend ? r : nend - 1;
        short8 a = {0, 0, 0, 0, 0, 0, 0, 0};
        if (lg < 2) {
            const float* xp = x + (size_t)rc * FEAT + lg * 8;
#pragma unroll
            for (int i = 0; i < 8; ++i) a[i] = (short)f2bu(xp[i]);
        }
#pragma unroll
        for (int jt = 0; jt < 8; ++jt) {
            const float bv = b1[jt * 16 + l15];
            f32x4 acc = {bv, bv, bv, bv};
            short8 b = *reinterpret_cast<const short8*>(&W1t[(jt * 16 + l15) * 32 + lg * 8]);
            acc = __builtin_amdgcn_mfma_f32_16x16x32_bf16(a, b, acc, 0, 0, 0);
#pragma unroll
            for (int rr = 0; rr < 4; ++rr)
                hsm[w * 32 + rt * 16 + lg * 4 + rr][jt * 16 + l15] =
                    f2bu(fmaxf(acc[rr], 0.0f));
        }
    }
    __syncthreads();

#pragma unroll
    for (int rt = 0; rt < 2; ++rt) {
        f32x4 acc[8];
#pragma unroll
        for (int jt = 0; jt < 8; ++jt) {
            const float bv = b2[jt * 16 + l15];
            f32x4 v = {bv, bv, bv, bv};
            acc[jt] = v;
        }
#pragma unroll
        for (int ks = 0; ks < 4; ++ks) {
            short8 a = *reinterpret_cast<const short8*>(&hsm[w * 32 + rt * 16 + l15][ks * 32 + lg * 8]);
#pragma unroll
            for (int jt = 0; jt < 8; ++jt) {
                short8 b = *reinterpret_cast<const short8*>(&W2t[(jt * 16 + l15) * HD + ks * 32 + lg * 8]);
                acc[jt] = __builtin_amdgcn_mfma_f32_16x16x32_bf16(a, b, acc[jt], 0, 0, 0);
            }
        }
#pragma unroll
        for (int jt = 0; jt < 8; ++jt)
#pragma unroll
            for (int rr = 0; rr < 4; ++rr) {
                const int row = rowb + w * 32 + rt * 16 + lg * 4 + rr;
                const ushort hv = f2bu(acc[jt][rr]);
                if (row < nend) hb[(size_t)row * HD + jt * 16 + l15] = hv;
                hsm[w * 32 + rt * 16 + lg * 4 + rr][jt * 16 + l15] = hv;
            }
        f32x4 acc3[8];
        const f32x4 zero = {0.f, 0.f, 0.f, 0.f};
#pragma unroll
        for (int jt = 0; jt < 8; ++jt) acc3[jt] = zero;
#pragma unroll
        for (int ks = 0; ks < 4; ++ks) {
            short8 a = *reinterpret_cast<const short8*>(&hsm[w * 32 + rt * 16 + l15][ks * 32 + lg * 8]);
#pragma unroll
            for (int jt = 0; jt < 8; ++jt) {
                short8 b = *reinterpret_cast<const short8*>(&Wtc[(jt * 16 + l15) * HD + ks * 32 + lg * 8]);
                acc3[jt] = __builtin_amdgcn_mfma_f32_16x16x32_bf16(a, b, acc3[jt], 0, 0, 0);
            }
        }
#pragma unroll
        for (int jt = 0; jt < 8; ++jt)
#pragma unroll
            for (int rr = 0; rr < 4; ++rr) {
                const int row = rowb + w * 32 + rt * 16 + lg * 4 + rr;
                if (row < nend)
                    hwb[(size_t)row * HD + jt * 16 + l15] = f2bu(acc3[jt][rr]);
            }
    }
}

// ---------------- hw = h @ conv_W[l]  (bf16 MFMA, bf16 out) ----------------
__global__ __launch_bounds__(256) void k_hw(
                     const ushort* __restrict__ hb, const ushort* __restrict__ Wt,
                     ushort* __restrict__ hwb) {
    const int lane = threadIdx.x & 63;
    const int w = threadIdx.x >> 6;
    const int row0 = blockIdx.x * 128 + w * 32;
    const int l15 = lane & 15, lg = lane >> 4;

    const f32x4 zero = {0.f, 0.f, 0.f, 0.f};
    f32x4 acc[2][8];
#pragma unroll
    for (int rt = 0; rt < 2; ++rt)
#pragma unroll
        for (int jt = 0; jt < 8; ++jt) acc[rt][jt] = zero;

#pragma unroll
    for (int ks = 0; ks < 4; ++ks) {
        short8 a[2];
#pragma unroll
        for (int rt = 0; rt < 2; ++rt) {
            int r = row0 + rt * 16 + l15;
            r = r < NN ? r : NN - 1;
            a[rt] = *reinterpret_cast<const short8*>(&hb[(size_t)r * HD + ks * 32 + lg * 8]);
        }
#pragma unroll
        for (int jt = 0; jt < 8; ++jt) {
            short8 b = *reinterpret_cast<const short8*>(&Wt[(jt * 16 + l15) * HD + ks * 32 + lg * 8]);
            acc[0][jt] = __builtin_amdgcn_mfma_f32_16x16x32_bf16(a[0], b, acc[0][jt], 0, 0, 0);
            acc[1][jt] = __builtin_amdgcn_mfma_f32_16x16x32_bf16(a[1], b, acc[1][jt], 0, 0, 0);
        }
    }
#pragma unroll
    for (int rt = 0; rt < 2; ++rt)
#pragma unroll
        for (int jt = 0; jt < 8; ++jt)
#pragma unroll
            for (int r = 0; r < 4; ++r) {
                int row = row0 + rt * 16 + lg * 4 + r;
                if (row < NN) hwb[(size_t)row * HD + jt * 16 + l15] = f2bu(acc[rt][jt][r]);
            }
}

// ---------------- gather + combine + refine MLP (MFMA) + bf16 residual ----------------
__global__ __launch_bounds__(512, 4) void k_combine(
                          const ushort* __restrict__ hwb,
                          const int* __restrict__ row_ptr,
                          const int* __restrict__ col,
                          const float* __restrict__ wgt,
                          const float* __restrict__ selfn,
                          const float* __restrict__ cb,
                          const ushort* __restrict__ Wt1, const float* __restrict__ b1,
                          const ushort* __restrict__ Wt2, const float* __restrict__ b2,
                          ushort* __restrict__ hb,
                          const int* __restrict__ perm) {
    const int t = threadIdx.x;
    const int n0 = blockIdx.x * 64;
    __shared__ ushort hs[64][LDP];
    __shared__ ushort hid[64][LDP];
    __shared__ int pm[64];
    __shared__ int rp0[64], rp1[64];

    if (t < 64) {
        const int idx = n0 + t;
        const int node = (idx < NN) ? perm[idx] : -1;
        pm[t] = node;
        const int nc = node >= 0 ? node : 0;
        rp0[t] = row_ptr[nc];
        rp1[t] = node >= 0 ? row_ptr[nc + 1] : row_ptr[nc];
    }
    __syncthreads();

    const int lane = t & 63, w = t >> 6;
    {   // gather phase (2-cluster form)
        const int c0 = 2 * lane;
        const float cbx = cb[c0], cby = cb[c0 + 1];
        float accx[8], accy[8];
        int ecur[8], eend[8];
        int rounds = 0;
#pragma unroll
        for (int m = 0; m < 8; ++m) {
            const int node = pm[w * 8 + m];
            const int nc = node >= 0 ? node : 0;
            const uint hv = *reinterpret_cast<const uint*>(&hwb[(size_t)nc * HD + c0]);
            const float sn = selfn[nc];
            accx[m] = bu2f((ushort)(hv & 0xffffu)) * sn + cbx;
            accy[m] = bu2f((ushort)(hv >> 16)) * sn + cby;
            ecur[m] = rp0[w * 8 + m];
            eend[m] = rp1[w * 8 + m];
            rounds = max(rounds, eend[m] - ecur[m]);
        }
#pragma unroll 1
        for (int r = 0; r < rounds; r += 2) {
            uint va[8], vb[8];
            float wa[8], wb[8];
            int ca[8], cc[8];
#pragma unroll
            for (int m = 0; m < 8; ++m) {
                const int e0 = ecur[m];
                const int a0 = (e0 < eend[m]) ? e0 : 0;
                const int a1 = (e0 + 1 < eend[m]) ? e0 + 1 : 0;
                wa[m] = (e0 < eend[m]) ? wgt[a0] : 0.0f;
                wb[m] = (e0 + 1 < eend[m]) ? wgt[a1] : 0.0f;
                ca[m] = col[a0];
                cc[m] = col[a1];
            }
#pragma unroll
            for (int m = 0; m < 8; ++m) {
                va[m] = *reinterpret_cast<const uint*>(&hwb[(size_t)ca[m] * HD + c0]);
                vb[m] = *reinterpret_cast<const uint*>(&hwb[(size_t)cc[m] * HD + c0]);
            }
#pragma unroll
            for (int m = 0; m < 8; ++m) {
                accx[m] += wa[m] * bu2f((ushort)(va[m] & 0xffffu));
                accy[m] += wa[m] * bu2f((ushort)(va[m] >> 16));
                accx[m] += wb[m] * bu2f((ushort)(vb[m] & 0xffffu));
                accy[m] += wb[m] * bu2f((ushort)(vb[m] >> 16));
            }
#pragma unroll
            for (int m = 0; m < 8; ++m) ecur[m] += 2;
        }
#pragma unroll
        for (int m = 0; m < 8; ++m) {
            const uint px = (uint)f2bu(fmaxf(accx[m], 0.0f));
            const uint py = (uint)f2bu(fmaxf(accy[m], 0.0f));
            *reinterpret_cast<uint*>(&hs[w * 8 + m][c0]) = px | (py << 16);
        }
    }
    __syncthreads();

    const int l15 = lane & 15, lg = lane >> 4;
    const int rt = (w & 3) * 16;           // row-tile base within block
    const int c0 = (w >> 2) * 64;          // col half base

    // GEMM1: hid = relu(hs @ W1 + b1)
    f32x4 acc1[4];
#pragma unroll
    for (int jt = 0; jt < 4; ++jt) {
        float bv = b1[c0 + jt * 16 + l15];
        f32x4 v = {bv, bv, bv, bv};
        acc1[jt] = v;
    }
#pragma unroll
    for (int ks = 0; ks < 4; ++ks) {
        short8 a = *reinterpret_cast<const short8*>(&hs[rt + l15][ks * 32 + lg * 8]);
#pragma unroll
        for (int jt = 0; jt < 4; ++jt) {
            short8 b = *reinterpret_cast<const short8*>(&Wt1[(c0 + jt * 16 + l15) * HD + ks * 32 + lg * 8]);
            acc1[jt] = __builtin_amdgcn_mfma_f32_16x16x32_bf16(a, b, acc1[jt], 0, 0, 0);
        }
    }
#pragma unroll
    for (int jt = 0; jt < 4; ++jt)
#pragma unroll
        for (int r = 0; r < 4; ++r)
            hid[rt + lg * 4 + r][c0 + jt * 16 + l15] = f2bu(fmaxf(acc1[jt][r], 0.0f));
    __syncthreads();

    // GEMM2: out = hid @ W2 + b2; hb[perm] += out (bf16 residual)
    f32x4 acc2[4];
#pragma unroll
    for (int jt = 0; jt < 4; ++jt) {
        float bv = b2[c0 + jt * 16 + l15];
        f32x4 v = {bv, bv, bv, bv};
        acc2[jt] = v;
    }
#pragma unroll
    for (int ks = 0; ks < 4; ++ks) {
        short8 a = *reinterpret_cast<const short8*>(&hid[rt + l15][ks * 32 + lg * 8]);
#pragma unroll
        for (int jt = 0; jt < 4; ++jt) {
            short8 b = *reinterpret_cast<const short8*>(&Wt2[(c0 + jt * 16 + l15) * HD + ks * 32 + lg * 8]);
            acc2[jt] = __builtin_amdgcn_mfma_f32_16x16x32_bf16(a, b, acc2[jt], 0, 0, 0);
        }
    }
#pragma unroll
    for (int jt = 0; jt < 4; ++jt)
#pragma unroll
        for (int r = 0; r < 4; ++r) {
            const int node = pm[rt + lg * 4 + r];
            if (node >= 0) {
                const size_t idx = (size_t)node * HD + c0 + jt * 16 + l15;
                hb[idx] = f2bu(acc2[jt][r] + bu2f(hb[idx]));
            }
        }
}

// ---------------- bernoulli head: (128 -> 64 -> 1), bf16 input ----------------
__global__ void k_bern(const ushort* __restrict__ hb,
                       const float* __restrict__ W1, const float* __restrict__ b1,
                       const float* __restrict__ W2, const float* __restrict__ b2,
                       float* __restrict__ out) {
    const long long t = (long long)blockIdx.x * blockDim.x + threadIdx.x;
    const int n = (int)(t >> 6);
    const int lane = (int)(t & 63);
    if (n >= NV) return;
    const ushort* hn = hb + (size_t)n * HD;
    float acc = b1[lane];
#pragma unroll 8
    for (int k = 0; k < HD; ++k) acc += bu2f(hn[k]) * W1[k * 64 + lane];
    float p = fmaxf(acc, 0.0f) * W2[lane];
#pragma unroll
    for (int off = 32; off > 0; off >>= 1) p += __shfl_down(p, off);
    if (lane == 0) out[n] = p + b2[0];
}

// ---------------- categorical head ----------------
__global__ void k_cat(const ushort* __restrict__ hb,
                      const float* __restrict__ cW, const float* __restrict__ cb,
                      float* __restrict__ out) {
    const long long t = (long long)blockIdx.x * blockDim.x + threadIdx.x;
    const int n = (int)(t >> 6);
    const int lane = (int)(t & 63);
    if (n >= NI) return;
    const ushort* hn = hb + (size_t)n * HD;
    float p[KK];
#pragma unroll
    for (int k = 0; k < KK; ++k) p[k] = 0.0f;
#pragma unroll
    for (int half = 0; half < 2; ++half) {
        const int hh = lane + 64 * half;
        const float vh = bu2f(hn[hh]);
        const float* wp = cW + ((size_t)n * HD + hh) * KK;
        const float4 w0 = *reinterpret_cast<const float4*>(wp);
        const float4 w1 = *reinterpret_cast<const float4*>(wp + 4);
        p[0] += vh * w0.x; p[1] += vh * w0.y; p[2] += vh * w0.z; p[3] += vh * w0.w;
        p[4] += vh * w1.x; p[5] += vh * w1.y; p[6] += vh * w1.z; p[7] += vh * w1.w;
    }
#pragma unroll
    for (int k = 0; k < KK; ++k) {
#pragma unroll
        for (int off = 32; off > 0; off >>= 1) p[k] += __shfl_down(p[k], off);
    }
    if (lane == 0) {
#pragma unroll
        for (int k = 0; k < KK; ++k) out[NV + (size_t)n * KK + k] = p[k] + cb[(size_t)n * KK + k];
    }
}

extern "C" void kernel_launch(void* const* d_in, const int* in_sizes, int n_in,
                              void* d_out, int out_size, void* d_ws, size_t ws_size,
                              hipStream_t stream) {
    const float* x  = (const float*)d_in[0];
    const int*   ei = (const int*)d_in[1];   // int inputs arrive as int32
    // d_in[2] = num_vars scalar (hardcoded NV)
    const float* ve_W1 = (const float*)d_in[3];
    const float* ve_b1 = (const float*)d_in[4];
    const float* ve_W2 = (const float*)d_in[5];
    const float* ve_b2 = (const float*)d_in[6];
    const float* ce_W1 = (const float*)d_in[7];
    const float* ce_b1 = (const float*)d_in[8];
    const float* ce_W2 = (const float*)d_in[9];
    const float* ce_b2 = (const float*)d_in[10];
    const float* conv_W = (const float*)d_in[11];
    const float* conv_b = (const float*)d_in[12];
    const float* ref_W1 = (const float*)d_in[13];
    const float* ref_b1 = (const float*)d_in[14];
    const float* ref_W2 = (const float*)d_in[15];
    const float* ref_b2 = (const float*)d_in[16];
    const float* bh_W1 = (const float*)d_in[17];
    const float* bh_b1 = (const float*)d_in[18];
    const float* bh_W2 = (const float*)d_in[19];
    const float* bh_b2 = (const float*)d_in[20];
    const float* cat_W = (const float*)d_in[21];
    const float* cat_b = (const float*)d_in[22];
    float* out = (float*)d_out;

    // ---- workspace layout (~86 MiB total) ----
    const size_t need = (size_t)(3 * NN + (NN + 1) + NN + 2 * NE + 2 * SCAN_BLK) * 4
                      + (size_t)3 * NN * HD * 2        // hwbA, hwbB(spare), hb bf16
                      + (size_t)12 * HD * HD * 2       // wt bf16
                      + (size_t)2 * WE_STRIDE * 2      // wte bf16
                      + (size_t)(3 * NDBUCK + NN) * 4; // hist + perm
    if (ws_size < need) return;

    float* deg     = (float*)d_ws;                   // NN
    float* dinv    = deg + NN;                       // NN
    float* selfn   = dinv + NN;                      // NN
    int*   row_ptr = (int*)(selfn + NN);             // NN+1
    int*   cnt     = row_ptr + (NN + 1);             // NN
    int*   col     = cnt + NN;                       // NE
    float* wgt     = (float*)(col + NE);             // NE
    int*   part    = (int*)(wgt + NE);               // SCAN_BLK
    int*   blockoff= part + SCAN_BLK;                // SCAN_BLK
    ushort* hwbA   = (ushort*)(blockoff + SCAN_BLK); // NN*HD bf16
    ushort* hwbB   = hwbA + (size_t)NN * HD;         // NN*HD bf16 (unused spare)
    ushort* hb     = hwbB + (size_t)NN * HD;         // NN*HD bf16
    ushort* wt     = hb + (size_t)NN * HD;           // 12*HD*HD bf16
    ushort* wte    = wt + (size_t)12 * HD * HD;      // 2*WE_STRIDE bf16
    int*   dhist   = (int*)(wte + (size_t)2 * WE_STRIDE); // NDBUCK
    int*   dbase   = dhist + NDBUCK;                 // NDBUCK
    int*   dcnt2   = dbase + NDBUCK;                 // NDBUCK
    int*   perm    = dcnt2 + NDBUCK;                 // NN

    // degree / norms / CSR / sort / weight prep
    k_deg_init<<<(NN + 255) / 256, 256, 0, stream>>>(deg);
    k_deg_scatter<<<(NE + 255) / 256, 256, 0, stream>>>(ei, deg);
    k_deg_fin<<<(NN + 255) / 256, 256, 0, stream>>>(deg, dinv, selfn);
    k_scan_part<<<SCAN_BLK, 256, 0, stream>>>(deg, part);
    k_scan_mid<<<1, 128, 0, stream>>>(part, blockoff, row_ptr);
    k_scan_apply<<<SCAN_BLK, 256, 0, stream>>>(deg, blockoff, row_ptr, cnt);
    k_csr_fill<<<(NE + 255) / 256, 256, 0, stream>>>(ei, row_ptr, cnt, dinv, col, wgt);
    k_hist_init<<<1, NDBUCK, 0, stream>>>(dhist, dcnt2);
    k_hist<<<(NN + 255) / 256, 256, 0, stream>>>(deg, dhist);
    k_hist_scan<<<1, NDBUCK, 0, stream>>>(dhist, dbase);
    k_perm_fill<<<(NN + 255) / 256, 256, 0, stream>>>(deg, dbase, dcnt2, perm);
    k_wprep<<<12 * 128, 128, 0, stream>>>(conv_W, ref_W1, ref_W2, wt);
    k_wprep_embed<<<256, 128, 0, stream>>>(ve_W1, ve_W2, ce_W1, ce_W2, wte);

    // embedding (MFMA) + fused conv_W[0] matmul, per side
    k_embed_mfma<<<(NV + 127) / 128, 256, 0, stream>>>(
        x, wte, ve_b1, wte + 128 * 32, ve_b2, wt, 0, NV, hb, hwbA);
    k_embed_mfma<<<(NN - NV + 127) / 128, 256, 0, stream>>>(
        x, wte + WE_STRIDE, ce_b1, wte + WE_STRIDE + 128 * 32, ce_b2, wt, NV, NN, hb, hwbA);

    // conv layers
    for (int l = 0; l < NL; ++l) {
        if (l > 0)
            k_hw<<<(NN + 127) / 128, 256, 0, stream>>>(hb, wt + (size_t)l * HD * HD, hwbA);
        k_combine<<<(NN + 63) / 64, 512, 0, stream>>>(hwbA, row_ptr, col, wgt, selfn,
                                               conv_b + (size_t)l * HD,
                                               wt + (size_t)(4 + l) * HD * HD,
                                               ref_b1 + (size_t)l * HD,
                                               wt + (size_t)(8 + l) * HD * HD,
                                               ref_b2 + (size_t)l * HD,
                                               hb, perm);
    }

    // heads
    k_bern<<<(NV * 64) / 256, 256, 0, stream>>>(hb, bh_W1, bh_b1, bh_W2, bh_b2, out);
    k_cat<<<(NI * 64) / 256, 256, 0, stream>>>(hb, cat_W, cat_b, out);
}

// Round 25
// 748.304 us; speedup vs baseline: 2.0443x; 1.0743x over previous
//
#include <hip/hip_runtime.h>
#include <hip/hip_bf16.h>

// r24 + bern head converted to MFMA (was 128 serial scalar loads/lane).
// Combine plateau confirmed at ~112us across 10 structural experiments.

#define NN 100000   // nodes
#define NV 50000    // vars
#define NE 640000   // edges
#define FEAT 16
#define HD 128
#define NL 4
#define NI 20000    // n_int
#define KK 8
#define SCAN_BLK 98 // ceil(NN / 1024)
#define LDP 136     // padded LDS row stride (bf16 elems)
#define WE_STRIDE (128*32 + 128*128)   // per-side embed weight stride (ushorts)
#define NDBUCK 256  // degree buckets for counting sort

typedef __hip_bfloat16 bf16;
typedef __attribute__((ext_vector_type(8))) short short8;
typedef __attribute__((ext_vector_type(4))) float f32x4;

static __device__ __forceinline__ ushort f2bu(float f) {
    __hip_bfloat16 b = __float2bfloat16(f);
    return *reinterpret_cast<ushort*>(&b);
}
static __device__ __forceinline__ float bu2f(ushort u) {
    __hip_bfloat16 b = *reinterpret_cast<__hip_bfloat16*>(&u);
    return __bfloat162float(b);
}

// ---------------- degree / norm ----------------
__global__ void k_deg_init(float* deg) {
    int i = blockIdx.x * blockDim.x + threadIdx.x;
    if (i < NN) deg[i] = 1.0f;
}

__global__ void k_deg_scatter(const int* __restrict__ ei, float* deg) {
    int e = blockIdx.x * blockDim.x + threadIdx.x;
    if (e < NE) atomicAdd(&deg[ei[NE + e]], 1.0f);
}

__global__ void k_deg_fin(const float* __restrict__ deg, float* dinv, float* selfn) {
    int i = blockIdx.x * blockDim.x + threadIdx.x;
    if (i < NN) {
        float d = deg[i];
        dinv[i]  = rsqrtf(d);
        selfn[i] = 1.0f / d;
    }
}

// ---------------- multi-block exclusive scan of in-degree counts ----------------
__global__ void k_scan_part(const float* __restrict__ deg, int* __restrict__ part) {
    __shared__ int s[256];
    const int t = threadIdx.x;
    const int i = blockIdx.x * 1024 + t * 4;
    int sum = 0;
#pragma unroll
    for (int j = 0; j < 4; ++j)
        if (i + j < NN) sum += (int)deg[i + j] - 1;
    s[t] = sum;
    __syncthreads();
    for (int off = 128; off > 0; off >>= 1) {
        if (t < off) s[t] += s[t + off];
        __syncthreads();
    }
    if (t == 0) part[blockIdx.x] = s[0];
}

__global__ void k_scan_mid(const int* __restrict__ part, int* __restrict__ blockoff,
                           int* __restrict__ row_ptr) {
    __shared__ int s[128];
    const int t = threadIdx.x;
    int v = (t < SCAN_BLK) ? part[t] : 0;
    s[t] = v;
    __syncthreads();
    for (int off = 1; off < 128; off <<= 1) {
        int u = (t >= off) ? s[t - off] : 0;
        __syncthreads();
        s[t] += u;
        __syncthreads();
    }
    if (t < SCAN_BLK) blockoff[t] = s[t] - v;   // exclusive
    if (t == 0) row_ptr[NN] = NE;
}

__global__ void k_scan_apply(const float* __restrict__ deg,
                             const int* __restrict__ blockoff,
                             int* __restrict__ row_ptr, int* __restrict__ cnt) {
    __shared__ int s[256];
    const int t = threadIdx.x;
    const int i = blockIdx.x * 1024 + t * 4;
    int c[4];
    int tsum = 0;
#pragma unroll
    for (int j = 0; j < 4; ++j) {
        c[j] = (i + j < NN) ? (int)deg[i + j] - 1 : 0;
        tsum += c[j];
    }
    s[t] = tsum;
    __syncthreads();
    for (int off = 1; off < 256; off <<= 1) {
        int u = (t >= off) ? s[t - off] : 0;
        __syncthreads();
        s[t] += u;
        __syncthreads();
    }
    int off = blockoff[blockIdx.x] + s[t] - tsum;   // exclusive within block
#pragma unroll
    for (int j = 0; j < 4; ++j) {
        if (i + j < NN) {
            row_ptr[i + j] = off;
            cnt[i + j] = 0;
            off += c[j];
        }
    }
}

__global__ void k_csr_fill(const int* __restrict__ ei,
                           const int* __restrict__ row_ptr, int* __restrict__ cnt,
                           const float* __restrict__ dinv,
                           int* __restrict__ col, float* __restrict__ wgt) {
    int e = blockIdx.x * blockDim.x + threadIdx.x;
    if (e >= NE) return;
    const int s = ei[e];
    const int d = ei[NE + e];
    const int pos = row_ptr[d] + atomicAdd(&cnt[d], 1);
    col[pos] = s;
    wgt[pos] = dinv[s] * dinv[d];
}

// ---------------- counting sort of nodes by in-degree (LDS-aggregated) ----------------
__global__ void k_hist_init(int* dhist, int* dcnt2) {
    int i = threadIdx.x;
    dhist[i] = 0;
    dcnt2[i] = 0;
}

__global__ void k_hist(const float* __restrict__ deg, int* __restrict__ dhist) {
    __shared__ int lh[NDBUCK];
    for (int b = threadIdx.x; b < NDBUCK; b += 256) lh[b] = 0;
    __syncthreads();
    const int i = blockIdx.x * 256 + threadIdx.x;
    if (i < NN) {
        int d = (int)deg[i] - 1;
        atomicAdd(&lh[d < NDBUCK ? d : NDBUCK - 1], 1);
    }
    __syncthreads();
    for (int b = threadIdx.x; b < NDBUCK; b += 256)
        if (lh[b]) atomicAdd(&dhist[b], lh[b]);
}

__global__ void k_hist_scan(const int* __restrict__ dhist, int* __restrict__ dbase) {
    __shared__ int s[NDBUCK];
    const int t = threadIdx.x;
    int v = dhist[t];
    s[t] = v;
    __syncthreads();
    for (int off = 1; off < NDBUCK; off <<= 1) {
        int u = (t >= off) ? s[t - off] : 0;
        __syncthreads();
        s[t] += u;
        __syncthreads();
    }
    dbase[t] = s[t] - v;   // exclusive
}

__global__ void k_perm_fill(const float* __restrict__ deg,
                            const int* __restrict__ dbase, int* __restrict__ dcnt2,
                            int* __restrict__ perm) {
    __shared__ int lcnt[NDBUCK];
    __shared__ int lbase[NDBUCK];
    for (int b = threadIdx.x; b < NDBUCK; b += 256) lcnt[b] = 0;
    __syncthreads();
    const int i = blockIdx.x * 256 + threadIdx.x;
    int d = 0, lr = 0;
    bool live = i < NN;
    if (live) {
        d = (int)deg[i] - 1;
        d = d < NDBUCK ? d : NDBUCK - 1;
        lr = atomicAdd(&lcnt[d], 1);
    }
    __syncthreads();
    for (int b = threadIdx.x; b < NDBUCK; b += 256)
        lbase[b] = lcnt[b] ? atomicAdd(&dcnt2[b], lcnt[b]) : 0;
    __syncthreads();
    if (live) perm[dbase[d] + lbase[d] + lr] = i;
}

// ---------------- weight prep: conv/refine fp32 [k][j] -> bf16 transposed [j][k] ----------------
__global__ void k_wprep(const float* __restrict__ conv_W,
                        const float* __restrict__ ref_W1,
                        const float* __restrict__ ref_W2,
                        ushort* __restrict__ wt) {
    const int mat = blockIdx.x >> 7;
    const int j = blockIdx.x & 127;
    const int k = threadIdx.x;
    const float* src = (mat < 4) ? conv_W + (size_t)mat * HD * HD
                     : (mat < 8) ? ref_W1 + (size_t)(mat - 4) * HD * HD
                                 : ref_W2 + (size_t)(mat - 8) * HD * HD;
    wt[(size_t)mat * HD * HD + j * HD + k] = f2bu(src[k * HD + j]);
}

// ---------------- embed weight prep ----------------
__global__ void k_wprep_embed(const float* __restrict__ vW1, const float* __restrict__ vW2,
                              const float* __restrict__ cW1, const float* __restrict__ cW2,
                              ushort* __restrict__ wte) {
    const int side = blockIdx.x >> 7;
    const int j = blockIdx.x & 127;
    const int k = threadIdx.x;   // 0..127
    const float* W1 = side ? cW1 : vW1;
    const float* W2 = side ? cW2 : vW2;
    ushort* o = wte + (size_t)side * WE_STRIDE;
    if (k < 32) o[j * 32 + k] = (k < FEAT) ? f2bu(W1[k * HD + j]) : (ushort)0;
    o[128 * 32 + j * HD + k] = f2bu(W2[k * HD + j]);
}

// ---------------- bern weight prep: bh_W1 (128x64) -> bf16 [j][128] ----------------
__global__ void k_wprep_bern(const float* __restrict__ W1, ushort* __restrict__ w1bt) {
    const int j = blockIdx.x;    // 0..63
    const int k = threadIdx.x;   // 0..127
    w1bt[j * HD + k] = f2bu(W1[k * 64 + j]);
}

// ---------------- embedding MLP via MFMA; writes hb + hw(layer0) ----------------
__global__ __launch_bounds__(256, 4) void k_embed_mfma(
        const float* __restrict__ x,
        const ushort* __restrict__ W1t, const float* __restrict__ b1,
        const ushort* __restrict__ W2t, const float* __restrict__ b2,
        const ushort* __restrict__ Wtc,
        int nbase, int nend,
        ushort* __restrict__ hb, ushort* __restrict__ hwb) {
    const int lane = threadIdx.x & 63, w = threadIdx.x >> 6;
    const int l15 = lane & 15, lg = lane >> 4;
    const int rowb = nbase + blockIdx.x * 128;
    __shared__ ushort hsm[128][LDP];

#pragma unroll
    for (int rt = 0; rt < 2; ++rt) {
        const int r = rowb + w * 32 + rt * 16 + l15;
        const int rc = r < nend ? r : nend - 1;
        short8 a = {0, 0, 0, 0, 0, 0, 0, 0};
        if (lg < 2) {
            const float* xp = x + (size_t)rc * FEAT + lg * 8;
#pragma unroll
            for (int i = 0; i < 8; ++i) a[i] = (short)f2bu(xp[i]);
        }
#pragma unroll
        for (int jt = 0; jt < 8; ++jt) {
            const float bv = b1[jt * 16 + l15];
            f32x4 acc = {bv, bv, bv, bv};
            short8 b = *reinterpret_cast<const short8*>(&W1t[(jt * 16 + l15) * 32 + lg * 8]);
            acc = __builtin_amdgcn_mfma_f32_16x16x32_bf16(a, b, acc, 0, 0, 0);
#pragma unroll
            for (int rr = 0; rr < 4; ++rr)
                hsm[w * 32 + rt * 16 + lg * 4 + rr][jt * 16 + l15] =
                    f2bu(fmaxf(acc[rr], 0.0f));
        }
    }
    __syncthreads();

#pragma unroll
    for (int rt = 0; rt < 2; ++rt) {
        f32x4 acc[8];
#pragma unroll
        for (int jt = 0; jt < 8; ++jt) {
            const float bv = b2[jt * 16 + l15];
            f32x4 v = {bv, bv, bv, bv};
            acc[jt] = v;
        }
#pragma unroll
        for (int ks = 0; ks < 4; ++ks) {
            short8 a = *reinterpret_cast<const short8*>(&hsm[w * 32 + rt * 16 + l15][ks * 32 + lg * 8]);
#pragma unroll
            for (int jt = 0; jt < 8; ++jt) {
                short8 b = *reinterpret_cast<const short8*>(&W2t[(jt * 16 + l15) * HD + ks * 32 + lg * 8]);
                acc[jt] = __builtin_amdgcn_mfma_f32_16x16x32_bf16(a, b, acc[jt], 0, 0, 0);
            }
        }
#pragma unroll
        for (int jt = 0; jt < 8; ++jt)
#pragma unroll
            for (int rr = 0; rr < 4; ++rr) {
                const int row = rowb + w * 32 + rt * 16 + lg * 4 + rr;
                const ushort hv = f2bu(acc[jt][rr]);
                if (row < nend) hb[(size_t)row * HD + jt * 16 + l15] = hv;
                hsm[w * 32 + rt * 16 + lg * 4 + rr][jt * 16 + l15] = hv;
            }
        f32x4 acc3[8];
        const f32x4 zero = {0.f, 0.f, 0.f, 0.f};
#pragma unroll
        for (int jt = 0; jt < 8; ++jt) acc3[jt] = zero;
#pragma unroll
        for (int ks = 0; ks < 4; ++ks) {
            short8 a = *reinterpret_cast<const short8*>(&hsm[w * 32 + rt * 16 + l15][ks * 32 + lg * 8]);
#pragma unroll
            for (int jt = 0; jt < 8; ++jt) {
                short8 b = *reinterpret_cast<const short8*>(&Wtc[(jt * 16 + l15) * HD + ks * 32 + lg * 8]);
                acc3[jt] = __builtin_amdgcn_mfma_f32_16x16x32_bf16(a, b, acc3[jt], 0, 0, 0);
            }
        }
#pragma unroll
        for (int jt = 0; jt < 8; ++jt)
#pragma unroll
            for (int rr = 0; rr < 4; ++rr) {
                const int row = rowb + w * 32 + rt * 16 + lg * 4 + rr;
                if (row < nend)
                    hwb[(size_t)row * HD + jt * 16 + l15] = f2bu(acc3[jt][rr]);
            }
    }
}

// ---------------- hw = h @ conv_W[l]  (bf16 MFMA, bf16 out) ----------------
__global__ __launch_bounds__(256) void k_hw(
                     const ushort* __restrict__ hb, const ushort* __restrict__ Wt,
                     ushort* __restrict__ hwb) {
    const int lane = threadIdx.x & 63;
    const int w = threadIdx.x >> 6;
    const int row0 = blockIdx.x * 128 + w * 32;
    const int l15 = lane & 15, lg = lane >> 4;

    const f32x4 zero = {0.f, 0.f, 0.f, 0.f};
    f32x4 acc[2][8];
#pragma unroll
    for (int rt = 0; rt < 2; ++rt)
#pragma unroll
        for (int jt = 0; jt < 8; ++jt) acc[rt][jt] = zero;

#pragma unroll
    for (int ks = 0; ks < 4; ++ks) {
        short8 a[2];
#pragma unroll
        for (int rt = 0; rt < 2; ++rt) {
            int r = row0 + rt * 16 + l15;
            r = r < NN ? r : NN - 1;
            a[rt] = *reinterpret_cast<const short8*>(&hb[(size_t)r * HD + ks * 32 + lg * 8]);
        }
#pragma unroll
        for (int jt = 0; jt < 8; ++jt) {
            short8 b = *reinterpret_cast<const short8*>(&Wt[(jt * 16 + l15) * HD + ks * 32 + lg * 8]);
            acc[0][jt] = __builtin_amdgcn_mfma_f32_16x16x32_bf16(a[0], b, acc[0][jt], 0, 0, 0);
            acc[1][jt] = __builtin_amdgcn_mfma_f32_16x16x32_bf16(a[1], b, acc[1][jt], 0, 0, 0);
        }
    }
#pragma unroll
    for (int rt = 0; rt < 2; ++rt)
#pragma unroll
        for (int jt = 0; jt < 8; ++jt)
#pragma unroll
            for (int r = 0; r < 4; ++r) {
                int row = row0 + rt * 16 + lg * 4 + r;
                if (row < NN) hwb[(size_t)row * HD + jt * 16 + l15] = f2bu(acc[rt][jt][r]);
            }
}

// ---------------- gather + combine + refine MLP (MFMA) + bf16 residual ----------------
__global__ __launch_bounds__(512, 4) void k_combine(
                          const ushort* __restrict__ hwb,
                          const int* __restrict__ row_ptr,
                          const int* __restrict__ col,
                          const float* __restrict__ wgt,
                          const float* __restrict__ selfn,
                          const float* __restrict__ cb,
                          const ushort* __restrict__ Wt1, const float* __restrict__ b1,
                          const ushort* __restrict__ Wt2, const float* __restrict__ b2,
                          ushort* __restrict__ hb,
                          const int* __restrict__ perm) {
    const int t = threadIdx.x;
    const int n0 = blockIdx.x * 64;
    __shared__ ushort hs[64][LDP];
    __shared__ ushort hid[64][LDP];
    __shared__ int pm[64];
    __shared__ int rp0[64], rp1[64];

    if (t < 64) {
        const int idx = n0 + t;
        const int node = (idx < NN) ? perm[idx] : -1;
        pm[t] = node;
        const int nc = node >= 0 ? node : 0;
        rp0[t] = row_ptr[nc];
        rp1[t] = node >= 0 ? row_ptr[nc + 1] : row_ptr[nc];
    }
    __syncthreads();

    const int lane = t & 63, w = t >> 6;
    {   // gather phase (2-cluster form)
        const int c0 = 2 * lane;
        const float cbx = cb[c0], cby = cb[c0 + 1];
        float accx[8], accy[8];
        int ecur[8], eend[8];
        int rounds = 0;
#pragma unroll
        for (int m = 0; m < 8; ++m) {
            const int node = pm[w * 8 + m];
            const int nc = node >= 0 ? node : 0;
            const uint hv = *reinterpret_cast<const uint*>(&hwb[(size_t)nc * HD + c0]);
            const float sn = selfn[nc];
            accx[m] = bu2f((ushort)(hv & 0xffffu)) * sn + cbx;
            accy[m] = bu2f((ushort)(hv >> 16)) * sn + cby;
            ecur[m] = rp0[w * 8 + m];
            eend[m] = rp1[w * 8 + m];
            rounds = max(rounds, eend[m] - ecur[m]);
        }
#pragma unroll 1
        for (int r = 0; r < rounds; r += 2) {
            uint va[8], vb[8];
            float wa[8], wb[8];
            int ca[8], cc[8];
#pragma unroll
            for (int m = 0; m < 8; ++m) {
                const int e0 = ecur[m];
                const int a0 = (e0 < eend[m]) ? e0 : 0;
                const int a1 = (e0 + 1 < eend[m]) ? e0 + 1 : 0;
                wa[m] = (e0 < eend[m]) ? wgt[a0] : 0.0f;
                wb[m] = (e0 + 1 < eend[m]) ? wgt[a1] : 0.0f;
                ca[m] = col[a0];
                cc[m] = col[a1];
            }
#pragma unroll
            for (int m = 0; m < 8; ++m) {
                va[m] = *reinterpret_cast<const uint*>(&hwb[(size_t)ca[m] * HD + c0]);
                vb[m] = *reinterpret_cast<const uint*>(&hwb[(size_t)cc[m] * HD + c0]);
            }
#pragma unroll
            for (int m = 0; m < 8; ++m) {
                accx[m] += wa[m] * bu2f((ushort)(va[m] & 0xffffu));
                accy[m] += wa[m] * bu2f((ushort)(va[m] >> 16));
                accx[m] += wb[m] * bu2f((ushort)(vb[m] & 0xffffu));
                accy[m] += wb[m] * bu2f((ushort)(vb[m] >> 16));
            }
#pragma unroll
            for (int m = 0; m < 8; ++m) ecur[m] += 2;
        }
#pragma unroll
        for (int m = 0; m < 8; ++m) {
            const uint px = (uint)f2bu(fmaxf(accx[m], 0.0f));
            const uint py = (uint)f2bu(fmaxf(accy[m], 0.0f));
            *reinterpret_cast<uint*>(&hs[w * 8 + m][c0]) = px | (py << 16);
        }
    }
    __syncthreads();

    const int l15 = lane & 15, lg = lane >> 4;
    const int rt = (w & 3) * 16;           // row-tile base within block
    const int c0 = (w >> 2) * 64;          // col half base

    // GEMM1: hid = relu(hs @ W1 + b1)
    f32x4 acc1[4];
#pragma unroll
    for (int jt = 0; jt < 4; ++jt) {
        float bv = b1[c0 + jt * 16 + l15];
        f32x4 v = {bv, bv, bv, bv};
        acc1[jt] = v;
    }
#pragma unroll
    for (int ks = 0; ks < 4; ++ks) {
        short8 a = *reinterpret_cast<const short8*>(&hs[rt + l15][ks * 32 + lg * 8]);
#pragma unroll
        for (int jt = 0; jt < 4; ++jt) {
            short8 b = *reinterpret_cast<const short8*>(&Wt1[(c0 + jt * 16 + l15) * HD + ks * 32 + lg * 8]);
            acc1[jt] = __builtin_amdgcn_mfma_f32_16x16x32_bf16(a, b, acc1[jt], 0, 0, 0);
        }
    }
#pragma unroll
    for (int jt = 0; jt < 4; ++jt)
#pragma unroll
        for (int r = 0; r < 4; ++r)
            hid[rt + lg * 4 + r][c0 + jt * 16 + l15] = f2bu(fmaxf(acc1[jt][r], 0.0f));
    __syncthreads();

    // GEMM2: out = hid @ W2 + b2; hb[perm] += out (bf16 residual)
    f32x4 acc2[4];
#pragma unroll
    for (int jt = 0; jt < 4; ++jt) {
        float bv = b2[c0 + jt * 16 + l15];
        f32x4 v = {bv, bv, bv, bv};
        acc2[jt] = v;
    }
#pragma unroll
    for (int ks = 0; ks < 4; ++ks) {
        short8 a = *reinterpret_cast<const short8*>(&hid[rt + l15][ks * 32 + lg * 8]);
#pragma unroll
        for (int jt = 0; jt < 4; ++jt) {
            short8 b = *reinterpret_cast<const short8*>(&Wt2[(c0 + jt * 16 + l15) * HD + ks * 32 + lg * 8]);
            acc2[jt] = __builtin_amdgcn_mfma_f32_16x16x32_bf16(a, b, acc2[jt], 0, 0, 0);
        }
    }
#pragma unroll
    for (int jt = 0; jt < 4; ++jt)
#pragma unroll
        for (int r = 0; r < 4; ++r) {
            const int node = pm[rt + lg * 4 + r];
            if (node >= 0) {
                const size_t idx = (size_t)node * HD + c0 + jt * 16 + l15;
                hb[idx] = f2bu(acc2[jt][r] + bu2f(hb[idx]));
            }
        }
}

// ---------------- bernoulli head via MFMA: (128 -> 64 -> 1) ----------------
// 256 threads = 4 waves; 128 nodes/block. Layer1 = 32 MFMAs/wave; epilogue
// relu * W2[col], 16-lane shfl_xor row-reduce, + b2.
__global__ __launch_bounds__(256, 4) void k_bern_mfma(
        const ushort* __restrict__ hb,
        const ushort* __restrict__ W1t,   // [64][128] bf16
        const float* __restrict__ b1,     // [64]
        const float* __restrict__ W2,     // [64]
        const float* __restrict__ b2,     // [1]
        float* __restrict__ out) {
    const int lane = threadIdx.x & 63, w = threadIdx.x >> 6;
    const int l15 = lane & 15, lg = lane >> 4;
    const int row0 = blockIdx.x * 128 + w * 32;

    float part[2][4];
#pragma unroll
    for (int rt = 0; rt < 2; ++rt)
#pragma unroll
        for (int r = 0; r < 4; ++r) part[rt][r] = 0.f;

#pragma unroll
    for (int rt = 0; rt < 2; ++rt) {
        f32x4 acc[4];
#pragma unroll
        for (int jt = 0; jt < 4; ++jt) {
            const float bv = b1[jt * 16 + l15];
            f32x4 v = {bv, bv, bv, bv};
            acc[jt] = v;
        }
        int rr = row0 + rt * 16 + l15;
        rr = rr < NV ? rr : NV - 1;
#pragma unroll
        for (int ks = 0; ks < 4; ++ks) {
            short8 a = *reinterpret_cast<const short8*>(&hb[(size_t)rr * HD + ks * 32 + lg * 8]);
#pragma unroll
            for (int jt = 0; jt < 4; ++jt) {
                short8 b = *reinterpret_cast<const short8*>(&W1t[(jt * 16 + l15) * HD + ks * 32 + lg * 8]);
                acc[jt] = __builtin_amdgcn_mfma_f32_16x16x32_bf16(a, b, acc[jt], 0, 0, 0);
            }
        }
#pragma unroll
        for (int jt = 0; jt < 4; ++jt) {
            const float w2v = W2[jt * 16 + l15];
#pragma unroll
            for (int r = 0; r < 4; ++r)
                part[rt][r] += fmaxf(acc[jt][r], 0.0f) * w2v;
        }
    }
#pragma unroll
    for (int rt = 0; rt < 2; ++rt)
#pragma unroll
        for (int r = 0; r < 4; ++r) {
            float v = part[rt][r];
#pragma unroll
            for (int off = 1; off < 16; off <<= 1)
                v += __shfl_xor(v, off, 64);
            part[rt][r] = v;
        }
    if (l15 == 0) {
        const float bb = b2[0];
#pragma unroll
        for (int rt = 0; rt < 2; ++rt)
#pragma unroll
            for (int r = 0; r < 4; ++r) {
                const int row = row0 + rt * 16 + lg * 4 + r;
                if (row < NV) out[row] = part[rt][r] + bb;
            }
    }
}

// ---------------- categorical head ----------------
__global__ void k_cat(const ushort* __restrict__ hb,
                      const float* __restrict__ cW, const float* __restrict__ cb,
                      float* __restrict__ out) {
    const long long t = (long long)blockIdx.x * blockDim.x + threadIdx.x;
    const int n = (int)(t >> 6);
    const int lane = (int)(t & 63);
    if (n >= NI) return;
    const ushort* hn = hb + (size_t)n * HD;
    float p[KK];
#pragma unroll
    for (int k = 0; k < KK; ++k) p[k] = 0.0f;
#pragma unroll
    for (int half = 0; half < 2; ++half) {
        const int hh = lane + 64 * half;
        const float vh = bu2f(hn[hh]);
        const float* wp = cW + ((size_t)n * HD + hh) * KK;
        const float4 w0 = *reinterpret_cast<const float4*>(wp);
        const float4 w1 = *reinterpret_cast<const float4*>(wp + 4);
        p[0] += vh * w0.x; p[1] += vh * w0.y; p[2] += vh * w0.z; p[3] += vh * w0.w;
        p[4] += vh * w1.x; p[5] += vh * w1.y; p[6] += vh * w1.z; p[7] += vh * w1.w;
    }
#pragma unroll
    for (int k = 0; k < KK; ++k) {
#pragma unroll
        for (int off = 32; off > 0; off >>= 1) p[k] += __shfl_down(p[k], off);
    }
    if (lane == 0) {
#pragma unroll
        for (int k = 0; k < KK; ++k) out[NV + (size_t)n * KK + k] = p[k] + cb[(size_t)n * KK + k];
    }
}

extern "C" void kernel_launch(void* const* d_in, const int* in_sizes, int n_in,
                              void* d_out, int out_size, void* d_ws, size_t ws_size,
                              hipStream_t stream) {
    const float* x  = (const float*)d_in[0];
    const int*   ei = (const int*)d_in[1];   // int inputs arrive as int32
    // d_in[2] = num_vars scalar (hardcoded NV)
    const float* ve_W1 = (const float*)d_in[3];
    const float* ve_b1 = (const float*)d_in[4];
    const float* ve_W2 = (const float*)d_in[5];
    const float* ve_b2 = (const float*)d_in[6];
    const float* ce_W1 = (const float*)d_in[7];
    const float* ce_b1 = (const float*)d_in[8];
    const float* ce_W2 = (const float*)d_in[9];
    const float* ce_b2 = (const float*)d_in[10];
    const float* conv_W = (const float*)d_in[11];
    const float* conv_b = (const float*)d_in[12];
    const float* ref_W1 = (const float*)d_in[13];
    const float* ref_b1 = (const float*)d_in[14];
    const float* ref_W2 = (const float*)d_in[15];
    const float* ref_b2 = (const float*)d_in[16];
    const float* bh_W1 = (const float*)d_in[17];
    const float* bh_b1 = (const float*)d_in[18];
    const float* bh_W2 = (const float*)d_in[19];
    const float* bh_b2 = (const float*)d_in[20];
    const float* cat_W = (const float*)d_in[21];
    const float* cat_b = (const float*)d_in[22];
    float* out = (float*)d_out;

    // ---- workspace layout (~86 MiB total) ----
    const size_t need = (size_t)(3 * NN + (NN + 1) + NN + 2 * NE + 2 * SCAN_BLK) * 4
                      + (size_t)3 * NN * HD * 2        // hwbA, hwbB(spare), hb bf16
                      + (size_t)12 * HD * HD * 2       // wt bf16
                      + (size_t)2 * WE_STRIDE * 2      // wte bf16
                      + (size_t)64 * HD * 2            // w1bt bf16
                      + (size_t)(3 * NDBUCK + NN) * 4; // hist + perm
    if (ws_size < need) return;

    float* deg     = (float*)d_ws;                   // NN
    float* dinv    = deg + NN;                       // NN
    float* selfn   = dinv + NN;                      // NN
    int*   row_ptr = (int*)(selfn + NN);             // NN+1
    int*   cnt     = row_ptr + (NN + 1);             // NN
    int*   col     = cnt + NN;                       // NE
    float* wgt     = (float*)(col + NE);             // NE
    int*   part    = (int*)(wgt + NE);               // SCAN_BLK
    int*   blockoff= part + SCAN_BLK;                // SCAN_BLK
    ushort* hwbA   = (ushort*)(blockoff + SCAN_BLK); // NN*HD bf16
    ushort* hwbB   = hwbA + (size_t)NN * HD;         // NN*HD bf16 (unused spare)
    ushort* hb     = hwbB + (size_t)NN * HD;         // NN*HD bf16
    ushort* wt     = hb + (size_t)NN * HD;           // 12*HD*HD bf16
    ushort* wte    = wt + (size_t)12 * HD * HD;      // 2*WE_STRIDE bf16
    ushort* w1bt   = wte + (size_t)2 * WE_STRIDE;    // 64*HD bf16
    int*   dhist   = (int*)(w1bt + (size_t)64 * HD); // NDBUCK
    int*   dbase   = dhist + NDBUCK;                 // NDBUCK
    int*   dcnt2   = dbase + NDBUCK;                 // NDBUCK
    int*   perm    = dcnt2 + NDBUCK;                 // NN

    // degree / norms / CSR / sort / weight prep
    k_deg_init<<<(NN + 255) / 256, 256, 0, stream>>>(deg);
    k_deg_scatter<<<(NE + 255) / 256, 256, 0, stream>>>(ei, deg);
    k_deg_fin<<<(NN + 255) / 256, 256, 0, stream>>>(deg, dinv, selfn);
    k_scan_part<<<SCAN_BLK, 256, 0, stream>>>(deg, part);
    k_scan_mid<<<1, 128, 0, stream>>>(part, blockoff, row_ptr);
    k_scan_apply<<<SCAN_BLK, 256, 0, stream>>>(deg, blockoff, row_ptr, cnt);
    k_csr_fill<<<(NE + 255) / 256, 256, 0, stream>>>(ei, row_ptr, cnt, dinv, col, wgt);
    k_hist_init<<<1, NDBUCK, 0, stream>>>(dhist, dcnt2);
    k_hist<<<(NN + 255) / 256, 256, 0, stream>>>(deg, dhist);
    k_hist_scan<<<1, NDBUCK, 0, stream>>>(dhist, dbase);
    k_perm_fill<<<(NN + 255) / 256, 256, 0, stream>>>(deg, dbase, dcnt2, perm);
    k_wprep<<<12 * 128, 128, 0, stream>>>(conv_W, ref_W1, ref_W2, wt);
    k_wprep_embed<<<256, 128, 0, stream>>>(ve_W1, ve_W2, ce_W1, ce_W2, wte);
    k_wprep_bern<<<64, 128, 0, stream>>>(bh_W1, w1bt);

    // embedding (MFMA) + fused conv_W[0] matmul, per side
    k_embed_mfma<<<(NV + 127) / 128, 256, 0, stream>>>(
        x, wte, ve_b1, wte + 128 * 32, ve_b2, wt, 0, NV, hb, hwbA);
    k_embed_mfma<<<(NN - NV + 127) / 128, 256, 0, stream>>>(
        x, wte + WE_STRIDE, ce_b1, wte + WE_STRIDE + 128 * 32, ce_b2, wt, NV, NN, hb, hwbA);

    // conv layers
    for (int l = 0; l < NL; ++l) {
        if (l > 0)
            k_hw<<<(NN + 127) / 128, 256, 0, stream>>>(hb, wt + (size_t)l * HD * HD, hwbA);
        k_combine<<<(NN + 63) / 64, 512, 0, stream>>>(hwbA, row_ptr, col, wgt, selfn,
                                               conv_b + (size_t)l * HD,
                                               wt + (size_t)(4 + l) * HD * HD,
                                               ref_b1 + (size_t)l * HD,
                                               wt + (size_t)(8 + l) * HD * HD,
                                               ref_b2 + (size_t)l * HD,
                                               hb, perm);
    }

    // heads
    k_bern_mfma<<<(NV + 127) / 128, 256, 0, stream>>>(hb, w1bt, bh_b1, bh_W2, bh_b2, out);
    k_cat<<<(NI * 64) / 256, 256, 0, stream>>>(hb, cat_W, cat_b, out);
}